// Round 1
// 429.774 us; speedup vs baseline: 1.0927x; 1.0927x over previous
//
#include <hip/hip_runtime.h>
#include <cstddef>

// ---- problem constants ----
constexpr int kN  = 16;
constexpr int kI  = 128;
constexpr int kHW = 24;
constexpr int kQ  = 576;    // 24*24
constexpr int kD  = 484;    // 22*22
constexpr int kDP = 512;    // padded d
constexpr int kPP = 676;    // 26*26 padded

// GEMM K-tiling
constexpr int kKT1 = 144;   // K1 = 4608 (= 2 src * 9 tap * 256 ic)
constexpr int kKT2 = 8;     // K2 = 256
constexpr int kKT3 = 8;     // K3 = 256

// ---- workspace layout ----
// half region (element offsets into _Float16*)
constexpr size_t H_XPAD   = 0;                          // [16][26][26][256] NHWC
constexpr size_t H_HPAD   = 2768896;                    // [16][26][26][256] NHWC
constexpr size_t H_APACK1 = 5537792;                    // 1792*4608 frag-tiled (256-row tiles)
constexpr size_t H_APACK2 = 13795328;                   // 1024*256 frag-tiled
constexpr size_t H_APACK3 = 14057472;                   // 256*256 frag-tiled
constexpr size_t H_A16    = 14123008;                   // [16][576][256]
constexpr size_t H_H16    = 16482304;                   // [16][576][256]
constexpr size_t H_Q16C   = 18841600;                   // [16][256][576]  (c-major)
constexpr size_t H_KT16   = 21200896;                   // [128 head][512 d][32 c]
constexpr size_t H_VC16   = 23298048;                   // [128 head][32 c][512 d]
constexpr size_t HALF_ELEMS = 25395200;
constexpr size_t HALF_BYTES = HALF_ELEMS * 2;           // 50,790,400
// float region at d_ws + HALF_BYTES
constexpr size_t F_G = 0;                               // [16][1024][576]

using half4    = __attribute__((ext_vector_type(4))) _Float16;
using half8    = __attribute__((ext_vector_type(8))) _Float16;
using floatx16 = __attribute__((ext_vector_type(16))) float;

__device__ __forceinline__ float sigm(float x) { return 1.0f / (1.0f + __expf(-x)); }
__device__ __forceinline__ float tanh_f(float x) {
    float e = __expf(2.0f * fabsf(x));
    float r = 1.0f - 2.0f / (e + 1.0f);
    return copysignf(r, x);
}

// 16B-aligned vector load/store (emits b128 ops)
__device__ __forceinline__ half8 LD8(const _Float16* p) { return *(const half8*)p; }
__device__ __forceinline__ void ST8(_Float16* p, half8 v) { *(half8*)p = v; }

// ---------------- weight packing ----------------
// Apack layout: [mt][kt][kk(2)][hl(2)][row(256)][j(8)] — exact A-fragment order,
// 256-row M-tiles (BM=256).
// K-order for gemm1: k = src*2304 + tap*256 + ic  (maps to source ic*9+tap)
__global__ void pack1_kernel(const float* __restrict__ wq_x, const float* __restrict__ wq_h,
                             const float* __restrict__ wk_x, const float* __restrict__ wk_h,
                             const float* __restrict__ wv_x, const float* __restrict__ wv_h,
                             const float* __restrict__ wg_x, const float* __restrict__ wg_h,
                             _Float16* __restrict__ dst) {
    int pidx = blockIdx.x * 256 + threadIdx.x;
    int j = pidx & 7, row = (pidx >> 3) & 255, hl = (pidx >> 11) & 1, kk = (pidx >> 12) & 1;
    int tile = pidx >> 13;
    int mt = tile / kKT1, kt = tile - mt * kKT1;
    int m = mt * 256 + row;
    int k = kt * 32 + kk * 16 + hl * 8 + j;
    int srcs = (k >= 2304) ? 1 : 0;
    int r = k - srcs * 2304;
    int tap = r >> 8, ic = r & 255;
    const float *s1, *s2; int mm;
    if (m < 256)      { s1 = wq_x; s2 = wq_h; mm = m; }
    else if (m < 512) { s1 = wk_x; s2 = wk_h; mm = m - 256; }
    else if (m < 768) { s1 = wv_x; s2 = wv_h; mm = m - 512; }
    else              { s1 = wg_x; s2 = wg_h; mm = m - 768; }
    const float* sp = srcs ? s2 : s1;
    dst[pidx] = (_Float16)sp[(size_t)mm * 2304 + ic * 9 + tap];
}

__global__ void pack_flat_kernel(const float* __restrict__ src, _Float16* __restrict__ dst,
                                 int Ktot, int Ktiles) {
    int pidx = blockIdx.x * 256 + threadIdx.x;
    int j = pidx & 7, row = (pidx >> 3) & 255, hl = (pidx >> 11) & 1, kk = (pidx >> 12) & 1;
    int tile = pidx >> 13;
    int mt = tile / Ktiles, kt = tile - mt * Ktiles;
    int m = mt * 256 + row;
    int k = kt * 32 + kk * 16 + hl * 8 + j;
    dst[pidx] = (_Float16)src[(size_t)m * Ktot + k];
}

// ---------------- input staging ----------------
// h0 [n][256][576] fp32 -> NHWC fp16 padded [n][26][26][256] (borders pre-zeroed)
__global__ void pad_nhwc_kernel(const float* __restrict__ src, _Float16* __restrict__ dst) {
    __shared__ float tile[32][65];
    int pxt = blockIdx.x, ict = blockIdx.y, n = blockIdx.z;
    int tid = threadIdx.x;
    {
        int icl = tid >> 6, pxl = tid & 63;
        #pragma unroll
        for (int rep = 0; rep < 8; ++rep) {
            int ic = ict * 32 + rep * 4 + icl;
            tile[rep * 4 + icl][pxl] = src[((size_t)n * 256 + ic) * kQ + pxt * 64 + pxl];
        }
    }
    __syncthreads();
    {
        int icl = tid & 31, pxl0 = tid >> 5;
        #pragma unroll
        for (int rep = 0; rep < 8; ++rep) {
            int pxl = rep * 8 + pxl0;
            int px = pxt * 64 + pxl;
            int y = px / kHW, x = px - y * kHW;
            dst[((size_t)n * kPP + (size_t)(y + 1) * 26 + (x + 1)) * 256 + ict * 32 + icl] =
                (_Float16)tile[icl][pxl];
        }
    }
}

// xin = 1x1 conv(x, w_in)+b_in -> NHWC fp16 padded
__global__ void conv1x1_pad_kernel(const float* __restrict__ x, const float* __restrict__ w,
                                   const float* __restrict__ b, _Float16* __restrict__ out) {
    int px = blockIdx.x * 64 + threadIdx.x;
    int n = blockIdx.z;
    int oc0 = __builtin_amdgcn_readfirstlane(blockIdx.y * 16 + threadIdx.y * 4);
    const float* ip = x + (size_t)n * kI * kQ + px;
    float acc[4] = {0.f, 0.f, 0.f, 0.f};
    #pragma unroll 4
    for (int ic = 0; ic < kI; ++ic) {
        float xv = ip[(size_t)ic * kQ];
        #pragma unroll
        for (int j = 0; j < 4; ++j) acc[j] = fmaf(xv, w[(size_t)(oc0 + j) * kI + ic], acc[j]);
    }
    int y = px / kHW, xc = px - y * kHW;
    _Float16* op = out + ((size_t)n * kPP + (size_t)(y + 1) * 26 + (xc + 1)) * 256 + oc0;
    #pragma unroll
    for (int j = 0; j < 4; ++j) op[j] = (_Float16)(acc[j] + b[oc0 + j]);
}

// ---------------- fused MFMA GEMM ----------------
// BM=256, BN=64, BK=32; 256 threads = 4 waves; wave wv owns rows wv*64..+63
// (two 32-row m-frags -> 2x2 accs per wave; LDS B reads amortized over 2 m-frags).
// A: direct global fragment loads from packed layout (no LDS), 1-tile prefetch.
// B: one half8/thread -> swizzled LDS (64B rows, chunk^=(row>>1)&3), 1-tile prefetch,
//    double-buffered, one barrier per K-tile, manual 2x unroll (Ktiles always even).
// Grid: x=nt (fast), y=n, z=mt (slow) so all XCDs share one L2-resident A slice.
// BMODE 0: B = on-the-fly im2col from two NHWC fp16 images, K=(src,tap,ic)
// BMODE 1: B = direct [n][576][Ktot] fp16 (channel-last)
// EMODE 0: m<256 -> q16c; 256..511 -> kT16; 512..767 -> vC16(+bias); 768.. -> gbuf
// EMODE 1: gates += : pf[idx] = acc + pf[idx] + bias[m]
// EMODE 2: out = acc + bias[m] -> pf
template<int BMODE, int EMODE>
__global__ __launch_bounds__(256, 3)
void gemm_kernel(const _Float16* __restrict__ Apack,
                 const _Float16* __restrict__ B1, const _Float16* __restrict__ B2,
                 _Float16* __restrict__ q16, _Float16* __restrict__ k16,
                 _Float16* __restrict__ v16, float* __restrict__ pf,
                 const float* __restrict__ bias, int Ktiles, int Ktot) {
    __shared__ _Float16 Bs[2][2048];
    const int tid = threadIdx.x;
    const int wv = tid >> 6, lane = tid & 63, l31 = lane & 31, hl = lane >> 5;
    const int nt = blockIdx.x, n = blockIdx.y, mt = blockIdx.z;

    floatx16 acc00 = {}, acc01 = {}, acc10 = {}, acc11 = {};

    // A packed [mt][kt][kk][hl][row256][j8]; per-kt tile = 8192 elems
    const _Float16* ap0 = Apack + (size_t)mt * Ktiles * 8192
                        + (size_t)hl * 2048 + (size_t)(wv * 64 + l31) * 8;   // kk=0
    const _Float16* ap1 = ap0 + 4096;                                        // kk=1

    const int px_l = tid >> 2, bc = tid & 3;
    const int px = nt * 64 + px_l;
    const int by = px / kHW, bx = px - by * kHW;

    // swizzled LDS offsets
    const int wofs = px_l * 32 + ((bc ^ ((px_l >> 1) & 3)) << 3);
    const int sw = (l31 >> 1) & 3;
    const int r00 = l31 * 32        + ((hl ^ sw) << 3);        // kk=0, cols 0..31
    const int r01 = (32 + l31) * 32 + ((hl ^ sw) << 3);        // kk=0, cols 32..63
    const int r10 = l31 * 32        + (((2 + hl) ^ sw) << 3);  // kk=1
    const int r11 = (32 + l31) * 32 + (((2 + hl) ^ sw) << 3);

    const _Float16 *bsx = nullptr, *bsh = nullptr;
    if (BMODE == 0) {
        size_t base = ((size_t)n * kPP + (size_t)by * 26 + bx) * 256 + (size_t)bc * 8;
        bsx = B1 + base;
        bsh = B2 + base;
    } else {
        bsx = B1 + ((size_t)n * kQ + px) * Ktot + bc * 8;
    }

    auto loadB = [&](int kt) -> half8 {
        if (BMODE == 0) {
            int srcs = (kt >= 72) ? 1 : 0;
            int t2 = kt - srcs * 72;
            int tap = t2 >> 3, ict = t2 & 7;
            int ty = (tap * 11) >> 5;          // tap/3 for 0..8
            int tx = tap - ty * 3;
            const _Float16* p = (srcs ? bsh : bsx) + ((size_t)(ty * 26 + tx)) * 256 + ict * 32;
            return LD8(p);
        } else {
            return LD8(bsx + kt * 32);
        }
    };

    // prologue: B(0), A(0)
    half8 bv = loadB(0);
    half8 a0 = LD8(ap0), a2 = LD8(ap0 + 256);   // mi=0/1, kk=0
    half8 a1 = LD8(ap1), a3 = LD8(ap1 + 256);   // mi=0/1, kk=1

    for (int kt = 0; kt < Ktiles; kt += 2) {
        // ---- even step: buffer 0 ----
        ST8(&Bs[0][wofs], bv);
        __syncthreads();
        bv = loadB(kt + 1);                                 // prefetch B(kt+1)
        half8 c0 = LD8(ap0 + 8192), c2 = LD8(ap0 + 8448);   // prefetch A(kt+1)
        half8 c1 = LD8(ap1 + 8192), c3 = LD8(ap1 + 8448);
        {
            const _Float16* bb = Bs[0];
            half8 b00 = LD8(bb + r00);
            half8 b01 = LD8(bb + r01);
            half8 b10 = LD8(bb + r10);
            half8 b11 = LD8(bb + r11);
            acc00 = __builtin_amdgcn_mfma_f32_32x32x16_f16(a0, b00, acc00, 0, 0, 0);
            acc01 = __builtin_amdgcn_mfma_f32_32x32x16_f16(a0, b01, acc01, 0, 0, 0);
            acc10 = __builtin_amdgcn_mfma_f32_32x32x16_f16(a2, b00, acc10, 0, 0, 0);
            acc11 = __builtin_amdgcn_mfma_f32_32x32x16_f16(a2, b01, acc11, 0, 0, 0);
            acc00 = __builtin_amdgcn_mfma_f32_32x32x16_f16(a1, b10, acc00, 0, 0, 0);
            acc01 = __builtin_amdgcn_mfma_f32_32x32x16_f16(a1, b11, acc01, 0, 0, 0);
            acc10 = __builtin_amdgcn_mfma_f32_32x32x16_f16(a3, b10, acc10, 0, 0, 0);
            acc11 = __builtin_amdgcn_mfma_f32_32x32x16_f16(a3, b11, acc11, 0, 0, 0);
        }
        // ---- odd step: buffer 1 ----
        ST8(&Bs[1][wofs], bv);
        __syncthreads();
        if (kt + 2 < Ktiles) {
            bv = loadB(kt + 2);                             // prefetch B(kt+2)
            a0 = LD8(ap0 + 16384); a2 = LD8(ap0 + 16640);   // prefetch A(kt+2)
            a1 = LD8(ap1 + 16384); a3 = LD8(ap1 + 16640);
        }
        {
            const _Float16* bb = Bs[1];
            half8 b00 = LD8(bb + r00);
            half8 b01 = LD8(bb + r01);
            half8 b10 = LD8(bb + r10);
            half8 b11 = LD8(bb + r11);
            acc00 = __builtin_amdgcn_mfma_f32_32x32x16_f16(c0, b00, acc00, 0, 0, 0);
            acc01 = __builtin_amdgcn_mfma_f32_32x32x16_f16(c0, b01, acc01, 0, 0, 0);
            acc10 = __builtin_amdgcn_mfma_f32_32x32x16_f16(c2, b00, acc10, 0, 0, 0);
            acc11 = __builtin_amdgcn_mfma_f32_32x32x16_f16(c2, b01, acc11, 0, 0, 0);
            acc00 = __builtin_amdgcn_mfma_f32_32x32x16_f16(c1, b10, acc00, 0, 0, 0);
            acc01 = __builtin_amdgcn_mfma_f32_32x32x16_f16(c1, b11, acc01, 0, 0, 0);
            acc10 = __builtin_amdgcn_mfma_f32_32x32x16_f16(c3, b10, acc10, 0, 0, 0);
            acc11 = __builtin_amdgcn_mfma_f32_32x32x16_f16(c3, b11, acc11, 0, 0, 0);
        }
        ap0 += 16384; ap1 += 16384;
    }

    // epilogue: C/D layout col=lane&31, row=(reg&3)+8*(reg>>2)+4*(lane>>5)
    const int mb0 = mt * 256 + wv * 64;
    #pragma unroll
    for (int mi = 0; mi < 2; ++mi) {
        #pragma unroll
        for (int ci = 0; ci < 2; ++ci) {
            const floatx16& av = mi ? (ci ? acc11 : acc10) : (ci ? acc01 : acc00);
            const int pxe = nt * 64 + ci * 32 + l31;
            #pragma unroll
            for (int r = 0; r < 16; ++r) {
                int rowi = (r & 3) + 8 * (r >> 2) + 4 * hl;
                int m = mb0 + mi * 32 + rowi;
                float val = av[r];
                if (EMODE == 0) {
                    if (m < 256) {
                        q16[((size_t)n * 256 + m) * kQ + pxe] = (_Float16)val;
                    } else if (m < 768) {
                        int ch = m & 255;
                        int yy = pxe / kHW, xx = pxe - yy * kHW;
                        if (yy >= 1 && yy <= 22 && xx >= 1 && xx <= 22) {
                            int d = (yy - 1) * 22 + (xx - 1);
                            int head = n * 8 + (ch >> 5);
                            if (m < 512)
                                k16[((size_t)head * kDP + d) * 32 + (ch & 31)] = (_Float16)val;
                            else
                                v16[((size_t)head * 32 + (ch & 31)) * kDP + d] = (_Float16)(val + bias[ch]);
                        }
                    } else {
                        pf[((size_t)n * 1024 + (m - 768)) * kQ + pxe] = val;
                    }
                } else if (EMODE == 1) {
                    size_t o = ((size_t)n * 1024 + m) * kQ + pxe;
                    pf[o] = val + pf[o] + bias[m];
                } else {
                    pf[((size_t)n * 256 + m) * kQ + pxe] = val + bias[m];
                }
            }
        }
    }
}

// ---------------- MFMA flash attention ----------------
__global__ __launch_bounds__(128)
void attn_kernel(const _Float16* __restrict__ q16c, const _Float16* __restrict__ kT16,
                 const _Float16* __restrict__ vC16, _Float16* __restrict__ a16) {
    const int lane = threadIdx.x & 63;
    const int wv   = threadIdx.x >> 6;
    const int l31 = lane & 31, hl = lane >> 5;
    const int head = blockIdx.y;            // n*8 + hd
    const int n = head >> 3, hd = head & 7;
    const int qt = blockIdx.x * 2 + wv;     // 0..17
    const int q0 = qt * 32;

    half8 qf0, qf1;
    {
        const _Float16* qb = q16c + ((size_t)n * 256 + hd * 32 + hl * 8) * kQ + q0 + l31;
        #pragma unroll
        for (int j = 0; j < 8; ++j) {
            qf0[j] = qb[(size_t)j * kQ];
            qf1[j] = qb[(size_t)(16 + j) * kQ];
        }
    }

    const _Float16* kbase0 = kT16 + ((size_t)head * kDP + l31) * 32 + hl * 8;
    const _Float16* vbase0 = vC16 + ((size_t)head * 32 + l31) * kDP + hl * 8;

    floatx16 acc = {};
    float m_run = -1e30f, l_run = 0.f;

    half8 kf0 = LD8(kbase0);
    half8 kf1 = LD8(kbase0 + 16);

    for (int dt = 0; dt < 16; ++dt) {
        const int d0 = dt * 32;
        floatx16 S = {};
        S = __builtin_amdgcn_mfma_f32_32x32x16_f16(kf0, qf0, S, 0, 0, 0);
        S = __builtin_amdgcn_mfma_f32_32x32x16_f16(kf1, qf1, S, 0, 0, 0);

        half8 vf0 = LD8(vbase0 + d0);
        half8 vf1 = LD8(vbase0 + d0 + 16);
        if (dt < 15) {
            kf0 = LD8(kbase0 + (size_t)(d0 + 32) * 32);
            kf1 = LD8(kbase0 + (size_t)(d0 + 32) * 32 + 16);
        }

        if (dt == 15) {
            #pragma unroll
            for (int r = 0; r < 16; ++r)
                if (!(hl == 0 && r < 4)) S[r] = -1e30f;
        }

        float tmax = S[0];
        #pragma unroll
        for (int r = 1; r < 16; ++r) tmax = fmaxf(tmax, S[r]);
        tmax = fmaxf(tmax, __shfl_xor(tmax, 32));
        float mnew = fmaxf(m_run, tmax);
        float f = __expf(m_run - mnew);
        float p[16], psum = 0.f;
        #pragma unroll
        for (int r = 0; r < 16; ++r) { p[r] = __expf(S[r] - mnew); psum += p[r]; }
        psum += __shfl_xor(psum, 32);
        l_run = f * l_run + psum;
        #pragma unroll
        for (int r = 0; r < 16; ++r) acc[r] *= f;
        m_run = mnew;

        float other[16];
        #pragma unroll
        for (int r = 0; r < 16; ++r) other[r] = __shfl_xor(p[r], 32);
        half8 pf0, pf1;
        #pragma unroll
        for (int t = 0; t < 4; ++t) {
            pf0[t]     = (_Float16)(hl ? other[4 + t]  : p[t]);
            pf0[4 + t] = (_Float16)(hl ? p[4 + t]      : other[t]);
            pf1[t]     = (_Float16)(hl ? other[12 + t] : p[8 + t]);
            pf1[4 + t] = (_Float16)(hl ? p[12 + t]     : other[8 + t]);
        }

        acc = __builtin_amdgcn_mfma_f32_32x32x16_f16(vf0, pf0, acc, 0, 0, 0);
        acc = __builtin_amdgcn_mfma_f32_32x32x16_f16(vf1, pf1, acc, 0, 0, 0);
    }

    float inv = 1.f / l_run;
    _Float16* ap = a16 + ((size_t)n * kQ + q0 + l31) * 256 + hd * 32;
    #pragma unroll
    for (int r = 0; r < 16; ++r) {
        int c = (r & 3) + 8 * (r >> 2) + 4 * hl;
        ap[c] = (_Float16)(acc[r] * inv);
    }
}

// ---------------- LSTM elementwise ----------------
__global__ void lstm_kernel(const float* __restrict__ gates, const float* __restrict__ c0,
                            _Float16* __restrict__ h16) {
    int px = blockIdx.x * 64 + threadIdx.x;
    int r = blockIdx.y * 4 + threadIdx.y;
    int n = blockIdx.z;
    size_t base = (size_t)n * 1024 * kQ + px;
    float iv = gates[base + (size_t)r * kQ];
    float fv = gates[base + (size_t)(256 + r) * kQ];
    float gv = gates[base + (size_t)(512 + r) * kQ];
    float ov = gates[base + (size_t)(768 + r) * kQ];
    float c = sigm(fv) * c0[((size_t)n * 256 + r) * kQ + px] + sigm(iv) * tanh_f(gv);
    float h = sigm(ov) * tanh_f(c);
    h16[((size_t)n * kQ + px) * 256 + r] = (_Float16)h;
}

extern "C" void kernel_launch(void* const* d_in, const int* in_sizes, int n_in,
                              void* d_out, int out_size, void* d_ws, size_t ws_size,
                              hipStream_t stream) {
    (void)in_sizes; (void)n_in; (void)out_size; (void)ws_size;
    const float* x     = (const float*)d_in[0];
    const float* h0    = (const float*)d_in[1];
    const float* c0    = (const float*)d_in[2];
    const float* w_in  = (const float*)d_in[3];
    const float* b_in  = (const float*)d_in[4];
    const float* wq_x  = (const float*)d_in[5];
    const float* wq_h  = (const float*)d_in[6];
    const float* wk_x  = (const float*)d_in[7];
    const float* wk_h  = (const float*)d_in[8];
    const float* wv_x  = (const float*)d_in[9];
    const float* wv_h  = (const float*)d_in[10];
    const float* bv    = (const float*)d_in[11];
    const float* wg_a  = (const float*)d_in[12];
    const float* bg    = (const float*)d_in[13];
    const float* wg_x  = (const float*)d_in[14];
    const float* wg_h  = (const float*)d_in[15];
    const float* w_out = (const float*)d_in[16];
    const float* b_out = (const float*)d_in[17];

    _Float16* wh = (_Float16*)d_ws;
    _Float16* xpad16  = wh + H_XPAD;
    _Float16* hpad16  = wh + H_HPAD;
    _Float16* apack1  = wh + H_APACK1;
    _Float16* apack2  = wh + H_APACK2;
    _Float16* apack3  = wh + H_APACK3;
    _Float16* a16     = wh + H_A16;
    _Float16* h16     = wh + H_H16;
    _Float16* q16c    = wh + H_Q16C;
    _Float16* kT16    = wh + H_KT16;
    _Float16* vC16    = wh + H_VC16;
    float* gbuf = (float*)((char*)d_ws + HALF_BYTES) + F_G;

    // zero NHWC image borders (ws re-poisoned each launch)
    hipMemsetAsync(wh, 0, 11075584, stream);

    // weight packing (fragment-order, 256-row tiles)
    pack1_kernel<<<32256, 256, 0, stream>>>(wq_x, wq_h, wk_x, wk_h, wv_x, wv_h, wg_x, wg_h, apack1);
    pack_flat_kernel<<<1024, 256, 0, stream>>>(wg_a, apack2, 256, kKT2);
    pack_flat_kernel<<<256, 256, 0, stream>>>(w_out, apack3, 256, kKT3);

    // input staging (NHWC fp16)
    pad_nhwc_kernel<<<dim3(9, 8, kN), 256, 0, stream>>>(h0, hpad16);
    conv1x1_pad_kernel<<<dim3(9, 16, kN), dim3(64, 4), 0, stream>>>(x, w_in, b_in, xpad16);

    // fused q/k/v/gates3x3 GEMM: M=1792, K=4608, N=576 x 16 batches
    // grid: x=nt (fast), y=n, z=mt (slow) — same A slice L2-resident chipwide
    gemm_kernel<0, 0><<<dim3(9, kN, 7), 256, 0, stream>>>(
        apack1, xpad16, hpad16, q16c, kT16, vC16, gbuf, bv, kKT1, 0);

    // MFMA flash attention -> a16 [n][px][256]
    attn_kernel<<<dim3(9, 128), 128, 0, stream>>>(q16c, kT16, vC16, a16);

    // gates += wg_a . a + bg : M=1024 -> 4 m-tiles
    gemm_kernel<1, 1><<<dim3(9, kN, 4), 256, 0, stream>>>(
        apack2, a16, nullptr, nullptr, nullptr, nullptr, gbuf, bg, kKT2, 256);

    // LSTM -> h16 [n][px][256]
    lstm_kernel<<<dim3(9, 64, kN), dim3(64, 4), 0, stream>>>(gbuf, c0, h16);

    // out = w_out . h + b_out : M=256 -> 1 m-tile
    gemm_kernel<1, 2><<<dim3(9, kN, 1), 256, 0, stream>>>(
        apack3, h16, nullptr, nullptr, nullptr, nullptr, (float*)d_out, b_out, kKT3, 256);
}

// Round 2
// 425.089 us; speedup vs baseline: 1.1047x; 1.0110x over previous
//
#include <hip/hip_runtime.h>
#include <cstddef>

// ---- problem constants ----
constexpr int kN  = 16;
constexpr int kI  = 128;
constexpr int kHW = 24;
constexpr int kQ  = 576;    // 24*24
constexpr int kD  = 484;    // 22*22
constexpr int kDP = 512;    // padded d
constexpr int kPP = 676;    // 26*26 padded

// GEMM K-tiling
constexpr int kKT1 = 144;   // K1 = 4608 (= 2 src * 9 tap * 256 ic)
constexpr int kKT2 = 8;     // K2 = 256
constexpr int kKT3 = 8;     // K3 = 256

// ---- workspace layout ----
// half region (element offsets into _Float16*)
constexpr size_t H_XPAD   = 0;                          // [16][26][26][256] NHWC
constexpr size_t H_HPAD   = 2768896;                    // [16][26][26][256] NHWC
constexpr size_t H_APACK1 = 5537792;                    // 1792*4608 frag-tiled (256-row tiles)
constexpr size_t H_APACK2 = 13795328;                   // 1024*256 frag-tiled
constexpr size_t H_APACK3 = 14057472;                   // 256*256 frag-tiled
constexpr size_t H_A16    = 14123008;                   // [16][576][256]
constexpr size_t H_H16    = 16482304;                   // [16][576][256]
constexpr size_t H_Q16C   = 18841600;                   // [16][256][576]  (c-major)
constexpr size_t H_KT16   = 21200896;                   // [128 head][512 d][32 c]
constexpr size_t H_VC16   = 23298048;                   // [128 head][32 c][512 d]
constexpr size_t HALF_ELEMS = 25395200;
constexpr size_t HALF_BYTES = HALF_ELEMS * 2;           // 50,790,400
// float region at d_ws + HALF_BYTES
constexpr size_t F_G = 0;                               // [16][1024][576]

constexpr size_t kXHGap = H_HPAD - H_XPAD;              // hpad - xpad element gap

using half4    = __attribute__((ext_vector_type(4))) _Float16;
using half8    = __attribute__((ext_vector_type(8))) _Float16;
using floatx16 = __attribute__((ext_vector_type(16))) float;

__device__ __forceinline__ float sigm(float x) { return 1.0f / (1.0f + __expf(-x)); }
__device__ __forceinline__ float tanh_f(float x) {
    float e = __expf(2.0f * fabsf(x));
    float r = 1.0f - 2.0f / (e + 1.0f);
    return copysignf(r, x);
}

// 16B-aligned vector load/store (emits b128 ops)
__device__ __forceinline__ half8 LD8(const _Float16* p) { return *(const half8*)p; }
__device__ __forceinline__ void ST8(_Float16* p, half8 v) { *(half8*)p = v; }

// ---------------- weight packing ----------------
// Apack layout: [mt][kt][kk(2)][hl(2)][row(256)][j(8)] — exact A-fragment order,
// 256-row M-tiles (BM=256).
// K-order for gemm1: k = src*2304 + tap*256 + ic  (maps to source ic*9+tap)
// Gate rows (m>=768) are PERMUTED: dst row m' = 4*r + gate  <-  src row gate*256 + r
// so gemm2's epilogue can compute the LSTM per-lane (gate == reg&3).
__global__ void pack1_kernel(const float* __restrict__ wq_x, const float* __restrict__ wq_h,
                             const float* __restrict__ wk_x, const float* __restrict__ wk_h,
                             const float* __restrict__ wv_x, const float* __restrict__ wv_h,
                             const float* __restrict__ wg_x, const float* __restrict__ wg_h,
                             _Float16* __restrict__ dst) {
    int pidx = blockIdx.x * 256 + threadIdx.x;
    int j = pidx & 7, row = (pidx >> 3) & 255, hl = (pidx >> 11) & 1, kk = (pidx >> 12) & 1;
    int tile = pidx >> 13;
    int mt = tile / kKT1, kt = tile - mt * kKT1;
    int m = mt * 256 + row;
    int k = kt * 32 + kk * 16 + hl * 8 + j;
    int srcs = (k >= 2304) ? 1 : 0;
    int r = k - srcs * 2304;
    int tap = r >> 8, ic = r & 255;
    const float *s1, *s2; int mm;
    if (m < 256)      { s1 = wq_x; s2 = wq_h; mm = m; }
    else if (m < 512) { s1 = wk_x; s2 = wk_h; mm = m - 256; }
    else if (m < 768) { s1 = wv_x; s2 = wv_h; mm = m - 512; }
    else              { s1 = wg_x; s2 = wg_h; int mp = m - 768; mm = (mp & 3) * 256 + (mp >> 2); }
    const float* sp = srcs ? s2 : s1;
    dst[pidx] = (_Float16)sp[(size_t)mm * 2304 + ic * 9 + tap];
}

// PERM=1: dst row m <- src row (m&3)*256 + (m>>2)  (gate interleave for wg_a)
template<int PERM>
__global__ void pack_flat_kernel(const float* __restrict__ src, _Float16* __restrict__ dst,
                                 int Ktot, int Ktiles) {
    int pidx = blockIdx.x * 256 + threadIdx.x;
    int j = pidx & 7, row = (pidx >> 3) & 255, hl = (pidx >> 11) & 1, kk = (pidx >> 12) & 1;
    int tile = pidx >> 13;
    int mt = tile / Ktiles, kt = tile - mt * Ktiles;
    int m = mt * 256 + row;
    int k = kt * 32 + kk * 16 + hl * 8 + j;
    int mm = PERM ? ((m & 3) * 256 + (m >> 2)) : m;
    dst[pidx] = (_Float16)src[(size_t)mm * Ktot + k];
}

// ---------------- input staging ----------------
// h0 [n][256][576] fp32 -> NHWC fp16 padded [n][26][26][256] (borders pre-zeroed)
__global__ void pad_nhwc_kernel(const float* __restrict__ src, _Float16* __restrict__ dst) {
    __shared__ float tile[32][65];
    int pxt = blockIdx.x, ict = blockIdx.y, n = blockIdx.z;
    int tid = threadIdx.x;
    {
        int icl = tid >> 6, pxl = tid & 63;
        #pragma unroll
        for (int rep = 0; rep < 8; ++rep) {
            int ic = ict * 32 + rep * 4 + icl;
            tile[rep * 4 + icl][pxl] = src[((size_t)n * 256 + ic) * kQ + pxt * 64 + pxl];
        }
    }
    __syncthreads();
    {
        int icl = tid & 31, pxl0 = tid >> 5;
        #pragma unroll
        for (int rep = 0; rep < 8; ++rep) {
            int pxl = rep * 8 + pxl0;
            int px = pxt * 64 + pxl;
            int y = px / kHW, x = px - y * kHW;
            dst[((size_t)n * kPP + (size_t)(y + 1) * 26 + (x + 1)) * 256 + ict * 32 + icl] =
                (_Float16)tile[icl][pxl];
        }
    }
}

// xin = 1x1 conv(x, w_in)+b_in -> NHWC fp16 padded
__global__ void conv1x1_pad_kernel(const float* __restrict__ x, const float* __restrict__ w,
                                   const float* __restrict__ b, _Float16* __restrict__ out) {
    int px = blockIdx.x * 64 + threadIdx.x;
    int n = blockIdx.z;
    int oc0 = __builtin_amdgcn_readfirstlane(blockIdx.y * 16 + threadIdx.y * 4);
    const float* ip = x + (size_t)n * kI * kQ + px;
    float acc[4] = {0.f, 0.f, 0.f, 0.f};
    #pragma unroll 4
    for (int ic = 0; ic < kI; ++ic) {
        float xv = ip[(size_t)ic * kQ];
        #pragma unroll
        for (int j = 0; j < 4; ++j) acc[j] = fmaf(xv, w[(size_t)(oc0 + j) * kI + ic], acc[j]);
    }
    int y = px / kHW, xc = px - y * kHW;
    _Float16* op = out + ((size_t)n * kPP + (size_t)(y + 1) * 26 + (xc + 1)) * 256 + oc0;
    #pragma unroll
    for (int j = 0; j < 4; ++j) op[j] = (_Float16)(acc[j] + b[oc0 + j]);
}

// ---------------- fused MFMA GEMM ----------------
// BM=256, BN=64, BK=32; 256 threads = 4 waves; wave wv owns rows wv*64..+63
// (two 32-row m-frags -> 2x2 accs per wave; LDS B reads amortized over 2 m-frags).
// A: direct global fragment loads from packed layout (no LDS), 1-tile prefetch.
// B: one half8/thread -> swizzled LDS, double-buffered, **2-tile-deep** register
//    prefetch so the ST8-before-barrier never waits on HBM latency.
// OOB prefetches (last 2 kt) read allocated-but-unused workspace — never consumed.
// Grid: XCD-chunked bijective swizzle of the linear block id (nwg % 8 == 0) so each
// XCD works ~1 contiguous A slice + grouped-n B images (L2-resident).
// Residency: __launch_bounds__(256,4) -> 4 blocks/CU; 1008-block grid fully
// co-resident in a single round (total regs 124+4 = 128 = exactly the 4-wave cap).
// BMODE 0: B = on-the-fly im2col from two NHWC fp16 images, K=(src,tap,ic)
// BMODE 1: B = direct [n][576][Ktot] fp16 (channel-last)
// EMODE 0: m<256 -> q16c; 256..511 -> kT16; 512..767 -> vC16(+bias); 768.. -> gbuf
// EMODE 2: out = acc + bias[m] -> pf
// EMODE 3: fused gate+LSTM epilogue (gate rows interleaved m'=4r+g):
//          pre-act = acc + pf[m'] + bias[g*256+r]; c,h computed per-lane; h -> h16o
template<int BMODE, int EMODE>
__global__ __launch_bounds__(256, 4)
void gemm_kernel(const _Float16* __restrict__ Apack,
                 const _Float16* __restrict__ B1, const _Float16* __restrict__ B2,
                 _Float16* __restrict__ q16, _Float16* __restrict__ k16,
                 _Float16* __restrict__ v16, float* __restrict__ pf,
                 const float* __restrict__ bias, const float* __restrict__ c0p,
                 _Float16* __restrict__ h16o, int Ktiles, int Ktot) {
    __shared__ _Float16 Bs[2][2048];
    const int tid = threadIdx.x;
    const int wv = tid >> 6, lane = tid & 63, l31 = lane & 31, hl = lane >> 5;

    // XCD-chunked bijective block swizzle (grid is always 9 x 16 x Z, 144*Z % 8 == 0)
    const int lid = blockIdx.x + 9 * (blockIdx.y + 16 * blockIdx.z);
    const int cpx = 18 * gridDim.z;                 // nwg/8
    const int swz = (lid & 7) * cpx + (lid >> 3);
    const int nt = swz % 9;
    const int t9 = swz / 9;
    const int n = t9 & 15, mt = t9 >> 4;

    floatx16 acc00 = {}, acc01 = {}, acc10 = {}, acc11 = {};

    // A packed [mt][kt][kk][hl][row256][j8]; per-kt tile = 8192 elems
    const _Float16* ap0 = Apack + (size_t)mt * Ktiles * 8192
                        + (size_t)hl * 2048 + (size_t)(wv * 64 + l31) * 8;   // kk=0
    const _Float16* ap1 = ap0 + 4096;                                        // kk=1

    const int px_l = tid >> 2, bc = tid & 3;
    const int px = nt * 64 + px_l;
    const int by = px / kHW, bx = px - by * kHW;

    // swizzled LDS offsets
    const int wofs = px_l * 32 + ((bc ^ ((px_l >> 1) & 3)) << 3);
    const int sw = (l31 >> 1) & 3;
    const int r00 = l31 * 32        + ((hl ^ sw) << 3);        // kk=0, cols 0..31
    const int r01 = (32 + l31) * 32 + ((hl ^ sw) << 3);        // kk=0, cols 32..63
    const int r10 = l31 * 32        + (((2 + hl) ^ sw) << 3);  // kk=1
    const int r11 = (32 + l31) * 32 + (((2 + hl) ^ sw) << 3);

    const _Float16* bsx;
    if (BMODE == 0) {
        bsx = B1 + ((size_t)n * kPP + (size_t)by * 26 + bx) * 256 + (size_t)bc * 8;
    } else {
        bsx = B1 + ((size_t)n * kQ + px) * Ktot + bc * 8;
    }

    auto loadB = [&](int kt) -> half8 {
        if (BMODE == 0) {
            int srcs = (kt >= 72) ? 1 : 0;
            int t2 = kt - srcs * 72;
            int tap = t2 >> 3, ict = t2 & 7;
            int ty = (tap * 11) >> 5;          // tap/3 for 0..8
            int tx = tap - ty * 3;
            const _Float16* p = bsx + (size_t)srcs * kXHGap
                              + ((size_t)(ty * 26 + tx)) * 256 + ict * 32;
            return LD8(p);
        } else {
            return LD8(bsx + kt * 32);
        }
    };

    // prologue: B two tiles deep, A one tile
    half8 bv0 = loadB(0);
    half8 bv1 = loadB(1);
    half8 a0 = LD8(ap0), a2 = LD8(ap0 + 256);   // mi=0/1, kk=0
    half8 a1 = LD8(ap1), a3 = LD8(ap1 + 256);   // mi=0/1, kk=1

    for (int kt = 0; kt < Ktiles; kt += 2) {
        // ---- even step: buffer 0 holds tile kt ----
        ST8(&Bs[0][wofs], bv0);
        __syncthreads();
        bv0 = loadB(kt + 2);                                // 2-deep B prefetch
        half8 c0 = LD8(ap0 + 8192), c2 = LD8(ap0 + 8448);   // A(kt+1)
        half8 c1 = LD8(ap1 + 8192), c3 = LD8(ap1 + 8448);
        {
            const _Float16* bb = Bs[0];
            half8 b00 = LD8(bb + r00);
            half8 b01 = LD8(bb + r01);
            half8 b10 = LD8(bb + r10);
            half8 b11 = LD8(bb + r11);
            acc00 = __builtin_amdgcn_mfma_f32_32x32x16_f16(a0, b00, acc00, 0, 0, 0);
            acc01 = __builtin_amdgcn_mfma_f32_32x32x16_f16(a0, b01, acc01, 0, 0, 0);
            acc10 = __builtin_amdgcn_mfma_f32_32x32x16_f16(a2, b00, acc10, 0, 0, 0);
            acc11 = __builtin_amdgcn_mfma_f32_32x32x16_f16(a2, b01, acc11, 0, 0, 0);
            acc00 = __builtin_amdgcn_mfma_f32_32x32x16_f16(a1, b10, acc00, 0, 0, 0);
            acc01 = __builtin_amdgcn_mfma_f32_32x32x16_f16(a1, b11, acc01, 0, 0, 0);
            acc10 = __builtin_amdgcn_mfma_f32_32x32x16_f16(a3, b10, acc10, 0, 0, 0);
            acc11 = __builtin_amdgcn_mfma_f32_32x32x16_f16(a3, b11, acc11, 0, 0, 0);
        }
        // ---- odd step: buffer 1 holds tile kt+1 ----
        ST8(&Bs[1][wofs], bv1);
        __syncthreads();
        bv1 = loadB(kt + 3);                                // 2-deep B prefetch
        a0 = LD8(ap0 + 16384); a2 = LD8(ap0 + 16640);       // A(kt+2)
        a1 = LD8(ap1 + 16384); a3 = LD8(ap1 + 16640);
        {
            const _Float16* bb = Bs[1];
            half8 b00 = LD8(bb + r00);
            half8 b01 = LD8(bb + r01);
            half8 b10 = LD8(bb + r10);
            half8 b11 = LD8(bb + r11);
            acc00 = __builtin_amdgcn_mfma_f32_32x32x16_f16(c0, b00, acc00, 0, 0, 0);
            acc01 = __builtin_amdgcn_mfma_f32_32x32x16_f16(c0, b01, acc01, 0, 0, 0);
            acc10 = __builtin_amdgcn_mfma_f32_32x32x16_f16(c2, b00, acc10, 0, 0, 0);
            acc11 = __builtin_amdgcn_mfma_f32_32x32x16_f16(c2, b01, acc11, 0, 0, 0);
            acc00 = __builtin_amdgcn_mfma_f32_32x32x16_f16(c1, b10, acc00, 0, 0, 0);
            acc01 = __builtin_amdgcn_mfma_f32_32x32x16_f16(c1, b11, acc01, 0, 0, 0);
            acc10 = __builtin_amdgcn_mfma_f32_32x32x16_f16(c3, b10, acc10, 0, 0, 0);
            acc11 = __builtin_amdgcn_mfma_f32_32x32x16_f16(c3, b11, acc11, 0, 0, 0);
        }
        ap0 += 16384; ap1 += 16384;
    }

    // epilogue: C/D layout col=lane&31, row=(reg&3)+8*(reg>>2)+4*(lane>>5)
    if (EMODE == 3) {
        // fused gates+LSTM: reg q holds gate g=q&3 of channel rr (4 gates per reg-quad)
        const int rrb = mt * 64 + wv * 16;
        #pragma unroll
        for (int mi = 0; mi < 2; ++mi) {
            #pragma unroll
            for (int ci = 0; ci < 2; ++ci) {
                const floatx16& av = mi ? (ci ? acc11 : acc10) : (ci ? acc01 : acc00);
                const int pxe = nt * 64 + ci * 32 + l31;
                #pragma unroll
                for (int tq = 0; tq < 4; ++tq) {
                    int rr = rrb + mi * 8 + 2 * tq + hl;
                    size_t gb = ((size_t)n * 1024 + 4 * rr) * kQ + pxe;
                    float iv = av[4 * tq + 0] + pf[gb]          + bias[rr];
                    float fv = av[4 * tq + 1] + pf[gb + kQ]     + bias[256 + rr];
                    float gv = av[4 * tq + 2] + pf[gb + 2 * kQ] + bias[512 + rr];
                    float ov = av[4 * tq + 3] + pf[gb + 3 * kQ] + bias[768 + rr];
                    float cc = sigm(fv) * c0p[((size_t)n * 256 + rr) * kQ + pxe]
                             + sigm(iv) * tanh_f(gv);
                    float hh = sigm(ov) * tanh_f(cc);
                    h16o[((size_t)n * kQ + pxe) * 256 + rr] = (_Float16)hh;
                }
            }
        }
        return;
    }
    const int mb0 = mt * 256 + wv * 64;
    #pragma unroll
    for (int mi = 0; mi < 2; ++mi) {
        #pragma unroll
        for (int ci = 0; ci < 2; ++ci) {
            const floatx16& av = mi ? (ci ? acc11 : acc10) : (ci ? acc01 : acc00);
            const int pxe = nt * 64 + ci * 32 + l31;
            #pragma unroll
            for (int r = 0; r < 16; ++r) {
                int rowi = (r & 3) + 8 * (r >> 2) + 4 * hl;
                int m = mb0 + mi * 32 + rowi;
                float val = av[r];
                if (EMODE == 0) {
                    if (m < 256) {
                        q16[((size_t)n * 256 + m) * kQ + pxe] = (_Float16)val;
                    } else if (m < 768) {
                        int ch = m & 255;
                        int yy = pxe / kHW, xx = pxe - yy * kHW;
                        if (yy >= 1 && yy <= 22 && xx >= 1 && xx <= 22) {
                            int d = (yy - 1) * 22 + (xx - 1);
                            int head = n * 8 + (ch >> 5);
                            if (m < 512)
                                k16[((size_t)head * kDP + d) * 32 + (ch & 31)] = (_Float16)val;
                            else
                                v16[((size_t)head * 32 + (ch & 31)) * kDP + d] = (_Float16)(val + bias[ch]);
                        }
                    } else {
                        pf[((size_t)n * 1024 + (m - 768)) * kQ + pxe] = val;
                    }
                } else {
                    pf[((size_t)n * 256 + m) * kQ + pxe] = val + bias[m];
                }
            }
        }
    }
}

// ---------------- MFMA flash attention ----------------
__global__ __launch_bounds__(128)
void attn_kernel(const _Float16* __restrict__ q16c, const _Float16* __restrict__ kT16,
                 const _Float16* __restrict__ vC16, _Float16* __restrict__ a16) {
    const int lane = threadIdx.x & 63;
    const int wv   = threadIdx.x >> 6;
    const int l31 = lane & 31, hl = lane >> 5;
    // XCD-chunked swizzle (1152 blocks, 144/XCD): same-head blocks stay on one XCD
    const int lid = blockIdx.x + 9 * blockIdx.y;
    const int swz = (lid & 7) * 144 + (lid >> 3);
    const int bx = swz % 9, head = swz / 9;     // head = n*8 + hd
    const int n = head >> 3, hd = head & 7;
    const int qt = bx * 2 + wv;                 // 0..17
    const int q0 = qt * 32;

    half8 qf0, qf1;
    {
        const _Float16* qb = q16c + ((size_t)n * 256 + hd * 32 + hl * 8) * kQ + q0 + l31;
        #pragma unroll
        for (int j = 0; j < 8; ++j) {
            qf0[j] = qb[(size_t)j * kQ];
            qf1[j] = qb[(size_t)(16 + j) * kQ];
        }
    }

    const _Float16* kbase0 = kT16 + ((size_t)head * kDP + l31) * 32 + hl * 8;
    const _Float16* vbase0 = vC16 + ((size_t)head * 32 + l31) * kDP + hl * 8;

    floatx16 acc = {};
    float m_run = -1e30f, l_run = 0.f;

    half8 kf0 = LD8(kbase0);
    half8 kf1 = LD8(kbase0 + 16);

    for (int dt = 0; dt < 16; ++dt) {
        const int d0 = dt * 32;
        floatx16 S = {};
        S = __builtin_amdgcn_mfma_f32_32x32x16_f16(kf0, qf0, S, 0, 0, 0);
        S = __builtin_amdgcn_mfma_f32_32x32x16_f16(kf1, qf1, S, 0, 0, 0);

        half8 vf0 = LD8(vbase0 + d0);
        half8 vf1 = LD8(vbase0 + d0 + 16);
        if (dt < 15) {
            kf0 = LD8(kbase0 + (size_t)(d0 + 32) * 32);
            kf1 = LD8(kbase0 + (size_t)(d0 + 32) * 32 + 16);
        }

        if (dt == 15) {
            #pragma unroll
            for (int r = 0; r < 16; ++r)
                if (!(hl == 0 && r < 4)) S[r] = -1e30f;
        }

        float tmax = S[0];
        #pragma unroll
        for (int r = 1; r < 16; ++r) tmax = fmaxf(tmax, S[r]);
        tmax = fmaxf(tmax, __shfl_xor(tmax, 32));
        float mnew = fmaxf(m_run, tmax);
        float f = __expf(m_run - mnew);
        float p[16], psum = 0.f;
        #pragma unroll
        for (int r = 0; r < 16; ++r) { p[r] = __expf(S[r] - mnew); psum += p[r]; }
        psum += __shfl_xor(psum, 32);
        l_run = f * l_run + psum;
        #pragma unroll
        for (int r = 0; r < 16; ++r) acc[r] *= f;
        m_run = mnew;

        float other[16];
        #pragma unroll
        for (int r = 0; r < 16; ++r) other[r] = __shfl_xor(p[r], 32);
        half8 pf0, pf1;
        #pragma unroll
        for (int t = 0; t < 4; ++t) {
            pf0[t]     = (_Float16)(hl ? other[4 + t]  : p[t]);
            pf0[4 + t] = (_Float16)(hl ? p[4 + t]      : other[t]);
            pf1[t]     = (_Float16)(hl ? other[12 + t] : p[8 + t]);
            pf1[4 + t] = (_Float16)(hl ? p[12 + t]     : other[8 + t]);
        }

        acc = __builtin_amdgcn_mfma_f32_32x32x16_f16(vf0, pf0, acc, 0, 0, 0);
        acc = __builtin_amdgcn_mfma_f32_32x32x16_f16(vf1, pf1, acc, 0, 0, 0);
    }

    float inv = 1.f / l_run;
    _Float16* ap = a16 + ((size_t)n * kQ + q0 + l31) * 256 + hd * 32;
    #pragma unroll
    for (int r = 0; r < 16; ++r) {
        int c = (r & 3) + 8 * (r >> 2) + 4 * hl;
        ap[c] = (_Float16)(acc[r] * inv);
    }
}

extern "C" void kernel_launch(void* const* d_in, const int* in_sizes, int n_in,
                              void* d_out, int out_size, void* d_ws, size_t ws_size,
                              hipStream_t stream) {
    (void)in_sizes; (void)n_in; (void)out_size; (void)ws_size;
    const float* x     = (const float*)d_in[0];
    const float* h0    = (const float*)d_in[1];
    const float* c0    = (const float*)d_in[2];
    const float* w_in  = (const float*)d_in[3];
    const float* b_in  = (const float*)d_in[4];
    const float* wq_x  = (const float*)d_in[5];
    const float* wq_h  = (const float*)d_in[6];
    const float* wk_x  = (const float*)d_in[7];
    const float* wk_h  = (const float*)d_in[8];
    const float* wv_x  = (const float*)d_in[9];
    const float* wv_h  = (const float*)d_in[10];
    const float* bv    = (const float*)d_in[11];
    const float* wg_a  = (const float*)d_in[12];
    const float* bg    = (const float*)d_in[13];
    const float* wg_x  = (const float*)d_in[14];
    const float* wg_h  = (const float*)d_in[15];
    const float* w_out = (const float*)d_in[16];
    const float* b_out = (const float*)d_in[17];

    _Float16* wh = (_Float16*)d_ws;
    _Float16* xpad16  = wh + H_XPAD;
    _Float16* hpad16  = wh + H_HPAD;
    _Float16* apack1  = wh + H_APACK1;
    _Float16* apack2  = wh + H_APACK2;
    _Float16* apack3  = wh + H_APACK3;
    _Float16* a16     = wh + H_A16;
    _Float16* h16     = wh + H_H16;
    _Float16* q16c    = wh + H_Q16C;
    _Float16* kT16    = wh + H_KT16;
    _Float16* vC16    = wh + H_VC16;
    float* gbuf = (float*)((char*)d_ws + HALF_BYTES) + F_G;

    // zero NHWC image borders (ws re-poisoned each launch)
    hipMemsetAsync(wh, 0, 11075584, stream);

    // weight packing (fragment-order, 256-row tiles; gate rows interleaved)
    pack1_kernel<<<32256, 256, 0, stream>>>(wq_x, wq_h, wk_x, wk_h, wv_x, wv_h, wg_x, wg_h, apack1);
    pack_flat_kernel<1><<<1024, 256, 0, stream>>>(wg_a, apack2, 256, kKT2);
    pack_flat_kernel<0><<<256, 256, 0, stream>>>(w_out, apack3, 256, kKT3);

    // input staging (NHWC fp16)
    pad_nhwc_kernel<<<dim3(9, 8, kN), 256, 0, stream>>>(h0, hpad16);
    conv1x1_pad_kernel<<<dim3(9, 16, kN), dim3(64, 4), 0, stream>>>(x, w_in, b_in, xpad16);

    // fused q/k/v/gates3x3 GEMM: M=1792, K=4608, N=576 x 16 batches
    gemm_kernel<0, 0><<<dim3(9, kN, 7), 256, 0, stream>>>(
        apack1, xpad16, hpad16, q16c, kT16, vC16, gbuf, bv, nullptr, nullptr, kKT1, 0);

    // MFMA flash attention -> a16 [n][px][256]
    attn_kernel<<<dim3(9, 128), 128, 0, stream>>>(q16c, kT16, vC16, a16);

    // gates = wg_a . a + bg + gbuf, fused LSTM -> h16 [n][px][256]
    gemm_kernel<1, 3><<<dim3(9, kN, 4), 256, 0, stream>>>(
        apack2, a16, nullptr, nullptr, nullptr, nullptr, gbuf, bg, c0, h16, kKT2, 256);

    // out = w_out . h + b_out : M=256 -> 1 m-tile
    gemm_kernel<1, 2><<<dim3(9, kN, 1), 256, 0, stream>>>(
        apack3, h16, nullptr, nullptr, nullptr, nullptr, (float*)d_out, b_out, nullptr, nullptr, kKT3, 256);
}